// Round 1
// baseline (104.198 us; speedup 1.0000x reference)
//
#include <hip/hip_runtime.h>

#define NB 4096
#define DK 1024
#define EPSF 1e-6f
#define QS 32.0f          // fp4 pre-scale 2^5: normalized entries sigma=1/32 -> sigma=1

typedef __attribute__((ext_vector_type(8))) int   i32x8_t;
typedef __attribute__((ext_vector_type(4))) int   i32x4_t;
typedef __attribute__((ext_vector_type(4))) float f32x4_t;

#if defined(__has_builtin)
#if __has_builtin(__builtin_amdgcn_cvt_scalef32_pk_fp4_f32)
#define HW_FP4 1
#endif
#endif

// ---------------------------------------------------------------------------
// Global fp4 layout (r11 swizzle, halved): row,k -> p=row>>4, r=row&15,
// kb=k>>7, slot s=(k>>5)&3 (32 k / 16 B), nibble n=k&31:
//   byte offset = p*8192 + kb*1024 + r*64 + ((s^(r&3))<<4) + (n>>1), nibble n&1
// (p,kb) chunk = 1 KB contiguous -> one 64-lane x 16 B DMA.
// ---------------------------------------------------------------------------

__device__ __forceinline__ void async16(const void* g, void* lds) {
    __builtin_amdgcn_global_load_lds(
        (const __attribute__((address_space(1))) void*)g,
        (__attribute__((address_space(3))) void*)lds, 16, 0, 0);
}

// branchless e2m1 encode fallback: grid 0,.5,1,1.5,2,3,4,6.
__device__ __forceinline__ unsigned enc4(float v) {
    const float a = fabsf(v);
    unsigned c = (a >= 0.25f) + (a >= 0.75f) + (a >= 1.25f) + (a >= 1.75f)
               + (a >= 2.5f)  + (a >= 3.5f)  + (a >= 5.0f);
    return c | ((v < 0.f) ? 8u : 0u);
}

// ---------------------------------------------------------------------------
// Kernel 1: wave-per-row normalize -> fp4 e2m1 (x32) in swizzled layout;
// exact fp32 diagonal; zeroes rowsum/colsum/donecnt. Lane l owns k[16l,16l+16)
// -> 16 nibbles = 8 B, one dwordx2 store per matrix.
// r0 change: pack via v_cvt_scalef32_pk_fp4_f32 (1 instr / 2 values, scale=1.0
// neutral, values pre-scaled in f32) instead of ~14-instr/value enc4 chain.
// ---------------------------------------------------------------------------
__global__ __launch_bounds__(256) void normalize_rows(
    const float* __restrict__ x, const float* __restrict__ y,
    unsigned char* __restrict__ xq, unsigned char* __restrict__ yq,
    float* __restrict__ sdiag, float* __restrict__ zerobuf)
{
    const int t = threadIdx.x;
    const int gid = blockIdx.x * 256 + t;
    if (gid < 2 * NB) zerobuf[gid] = 0.f;                    // rowsum+colsum contiguous
    if (gid == 0) *((unsigned*)(zerobuf + 3 * NB)) = 0u;     // gemm done-counter

    const int wave = t >> 6;
    const int lane = t & 63;
    const int row  = blockIdx.x * 4 + wave;

    const float4* xr = reinterpret_cast<const float4*>(x + (size_t)row * DK);
    const float4* yr = reinterpret_cast<const float4*>(y + (size_t)row * DK);

    float4 xv[4], yv[4];
    float ssx = 0.f, ssy = 0.f, sxy = 0.f;
    #pragma unroll
    for (int jj = 0; jj < 4; ++jj) {
        xv[jj] = xr[lane * 4 + jj];
        yv[jj] = yr[lane * 4 + jj];
        ssx += xv[jj].x*xv[jj].x + xv[jj].y*xv[jj].y + xv[jj].z*xv[jj].z + xv[jj].w*xv[jj].w;
        ssy += yv[jj].x*yv[jj].x + yv[jj].y*yv[jj].y + yv[jj].z*yv[jj].z + yv[jj].w*yv[jj].w;
        sxy += xv[jj].x*yv[jj].x + xv[jj].y*yv[jj].y + xv[jj].z*yv[jj].z + xv[jj].w*yv[jj].w;
    }
    #pragma unroll
    for (int off = 1; off < 64; off <<= 1) {
        ssx += __shfl_xor(ssx, off, 64);
        ssy += __shfl_xor(ssy, off, 64);
        sxy += __shfl_xor(sxy, off, 64);
    }
    const float invx = 1.0f / fmaxf(sqrtf(ssx), EPSF);
    const float invy = 1.0f / fmaxf(sqrtf(ssy), EPSF);
    const float sx = invx * QS;
    const float sy = invy * QS;

    float fx[16], fy[16];
    #pragma unroll
    for (int jj = 0; jj < 4; ++jj) {
        fx[jj*4+0] = xv[jj].x; fx[jj*4+1] = xv[jj].y;
        fx[jj*4+2] = xv[jj].z; fx[jj*4+3] = xv[jj].w;
        fy[jj*4+0] = yv[jj].x; fy[jj*4+1] = yv[jj].y;
        fy[jj*4+2] = yv[jj].z; fy[jj*4+3] = yv[jj].w;
    }

    unsigned xb0, xb1, yb0, yb1;
#ifdef HW_FP4
    // byte m = {fp4(f[2m+1])<<4 | fp4(f[2m])}: pk convention src0 -> low nibble.
    // scale operand = 1.0f (2^0) -> neutral under either exponent-only or
    // full-multiply semantics; the real scale sx/sy is a plain f32 mul.
    #define CVT8(dst, f, s)                                                        \
        dst = __builtin_amdgcn_cvt_scalef32_pk_fp4_f32(0u,  (f)[0]*(s), (f)[1]*(s), 1.0f, 0); \
        dst = __builtin_amdgcn_cvt_scalef32_pk_fp4_f32(dst, (f)[2]*(s), (f)[3]*(s), 1.0f, 1); \
        dst = __builtin_amdgcn_cvt_scalef32_pk_fp4_f32(dst, (f)[4]*(s), (f)[5]*(s), 1.0f, 2); \
        dst = __builtin_amdgcn_cvt_scalef32_pk_fp4_f32(dst, (f)[6]*(s), (f)[7]*(s), 1.0f, 3)
    CVT8(xb0, fx,     sx);
    CVT8(xb1, fx + 8, sx);
    CVT8(yb0, fy,     sy);
    CVT8(yb1, fy + 8, sy);
    #undef CVT8
#else
    unsigned xb[2] = {0u, 0u}, yb[2] = {0u, 0u};
    #pragma unroll
    for (int j = 0; j < 16; ++j) {
        xb[j >> 3] |= enc4(fx[j] * sx) << ((j & 7) * 4);
        yb[j >> 3] |= enc4(fy[j] * sy) << ((j & 7) * 4);
    }
    xb0 = xb[0]; xb1 = xb[1]; yb0 = yb[0]; yb1 = yb[1];
#endif

    const int p = row >> 4, r = row & 15;
    const unsigned off = (unsigned)p * 8192 + (lane >> 3) * 1024 + r * 64
                       + ((((lane & 7) >> 1) ^ (r & 3)) << 4) + (lane & 1) * 8;
    *reinterpret_cast<uint2*>(xq + off) = make_uint2(xb0, xb1);
    *reinterpret_cast<uint2*>(yq + off) = make_uint2(yb0, yb1);

    if (lane == 0) sdiag[row] = sxy * invx * invy;
}

// ---------------------------------------------------------------------------
// Kernel 2: S' = 1024 * xn*yn^T via MX-fp4 (unit scales, cbsz=blgp=4),
// 256x256 tiles, 512 threads, grid 256 = 1 block/CU, double-buffered LDS
// (2 x 32 KB), raw s_waitcnt vmcnt(4) + raw s_barrier.
// r0 change: finalize fused as last-block epilogue (device-scope counter,
// release on counter-add / acquire on counter-read, agent-scope loads of the
// atomically-accumulated rowsum/colsum) -- removes kernel 3's launch + tail.
// ---------------------------------------------------------------------------
__global__ __launch_bounds__(512) void gemm_exp_sums(
    const unsigned char* __restrict__ xq, const unsigned char* __restrict__ yq,
    float* __restrict__ rowsum, float* __restrict__ colsum,
    const float* __restrict__ sdiag, unsigned* __restrict__ donecnt,
    float* __restrict__ out)
{
    __shared__ __align__(16) unsigned char LDS[2][32768];  // [buf][A:0-16K | B:16K-32K]
    __shared__ unsigned lastFlag;
    __shared__ double dred[8];

    const int t    = threadIdx.x;
    const int lane = t & 63;
    const int wave = t >> 6;        // 0..7
    const int q    = lane >> 4;
    const int l15  = lane & 15;

    const int R0 = blockIdx.y * 256;
    const int C0 = blockIdx.x * 256;
    const int wRow = (wave >> 2) * 64;   // 0 or 64 (second half at +128)
    const int wCol = (wave & 3) * 64;    // 0,64,128,192

    f32x4_t acc[2][4][4];
    #pragma unroll
    for (int hh = 0; hh < 2; hh++)
        #pragma unroll
        for (int i = 0; i < 4; i++)
            #pragma unroll
            for (int j = 0; j < 4; j++)
                acc[hh][i][j] = (f32x4_t){0.f, 0.f, 0.f, 0.f};

    // DMA sources: wave stages A panels {2w,2w+1}, B panels {2w,2w+1}.
    // fp4 panel stride 8192 B; (p,kb) chunk = 1 KB at p*8192 + kb*1024.
    const unsigned char* srcA =
        xq + (size_t)((R0 >> 4) + 2 * wave) * 8192 + lane * 16;
    const unsigned char* srcB =
        yq + (size_t)((C0 >> 4) + 2 * wave) * 8192 + lane * 16;

    const int sl = (q ^ (l15 & 3)) << 4;   // swizzled 16-B slot within row

    // one stage = 4 DMAs per wave
    auto issue = [&](int kb, int buf) {
        #pragma unroll
        for (int pp = 0; pp < 2; ++pp) {
            async16(srcA + pp * 8192 + kb * 1024,
                    &LDS[buf][(2 * wave + pp) * 1024]);
            async16(srcB + pp * 8192 + kb * 1024,
                    &LDS[buf][16384 + (2 * wave + pp) * 1024]);
        }
    };

    issue(0, 0);

    #pragma unroll 1
    for (int kb = 0; kb < 8; ++kb) {
        const int buf = kb & 1;
        if (kb < 7) {
            issue(kb + 1, buf ^ 1);
            __builtin_amdgcn_s_waitcnt(0xF74);   // vmcnt(4): prev stage's DMAs done
        } else {
            __builtin_amdgcn_s_waitcnt(0xF70);   // vmcnt(0): last stage
        }
        __builtin_amdgcn_s_barrier();

        i32x8_t bfr[4];
        #pragma unroll
        for (int nt = 0; nt < 4; ++nt) {
            const i32x4_t v = *reinterpret_cast<const i32x4_t*>(
                &LDS[buf][16384 + ((wCol >> 4) + nt) * 1024 + l15 * 64 + sl]);
            bfr[nt][0] = v[0]; bfr[nt][1] = v[1]; bfr[nt][2] = v[2]; bfr[nt][3] = v[3];
            bfr[nt][4] = 0;    bfr[nt][5] = 0;    bfr[nt][6] = 0;    bfr[nt][7] = 0;
        }
        #pragma unroll
        for (int hh = 0; hh < 2; ++hh) {
            #pragma unroll
            for (int mt = 0; mt < 4; ++mt) {
                const i32x4_t v = *reinterpret_cast<const i32x4_t*>(
                    &LDS[buf][((wRow >> 4) + hh * 8 + mt) * 1024 + l15 * 64 + sl]);
                i32x8_t af;
                af[0] = v[0]; af[1] = v[1]; af[2] = v[2]; af[3] = v[3];
                af[4] = 0;    af[5] = 0;    af[6] = 0;    af[7] = 0;
                #pragma unroll
                for (int nt = 0; nt < 4; ++nt)
                    acc[hh][mt][nt] = __builtin_amdgcn_mfma_scale_f32_16x16x128_f8f6f4(
                        af, bfr[nt], acc[hh][mt][nt],
                        4, 4,                       // cbsz=fp4(e2m1), blgp=fp4(e2m1)
                        0, 0x7F7F7F7F,              // A scales: E8M0 127 = 2^0
                        0, 0x7F7F7F7F);             // B scales: 2^0
            }
        }

        __builtin_amdgcn_s_barrier();  // reads of buf done before re-targeting
    }

    // Epilogue: acc holds 1024*S (32x32 pre-scale) -> E = exp2(acc/(1024*TAU*ln2)).
    const float kScale = (float)(1.0 / (1024.0 * 0.07 * 0.6931471805599453));
    float csum[4] = {0.f, 0.f, 0.f, 0.f};
    #pragma unroll
    for (int hh = 0; hh < 2; ++hh) {
        #pragma unroll
        for (int mt = 0; mt < 4; ++mt) {
            float rsum[4] = {0.f, 0.f, 0.f, 0.f};
            #pragma unroll
            for (int nt = 0; nt < 4; ++nt) {
                #pragma unroll
                for (int r = 0; r < 4; ++r) {
                    const float e = exp2f(acc[hh][mt][nt][r] * kScale);
                    rsum[r]  += e;
                    csum[nt] += e;
                }
            }
            #pragma unroll
            for (int r = 0; r < 4; ++r) {
                float v = rsum[r];
                v += __shfl_xor(v, 1, 64);
                v += __shfl_xor(v, 2, 64);
                v += __shfl_xor(v, 4, 64);
                v += __shfl_xor(v, 8, 64);
                if (l15 == 0)
                    atomicAdd(&rowsum[R0 + wRow + hh * 128 + mt * 16 + q * 4 + r], v);
            }
        }
    }
    #pragma unroll
    for (int nt = 0; nt < 4; ++nt) {
        float v = csum[nt];
        v += __shfl_xor(v, 16, 64);
        v += __shfl_xor(v, 32, 64);
        if (lane < 16)
            atomicAdd(&colsum[C0 + wCol + nt * 16 + l15], v);
    }

    // ---- fused finalize: last block computes the scalar loss ----
    __syncthreads();                       // all waves' atomics issued+complete
    if (t == 0) {
        __threadfence();
        const unsigned old = __hip_atomic_fetch_add(
            donecnt, 1u, __ATOMIC_ACQ_REL, __HIP_MEMORY_SCOPE_AGENT);
        lastFlag = (old == 255u) ? 1u : 0u;
    }
    __syncthreads();                       // lastFlag block-uniform
    if (lastFlag) {
        const float extra = (float)(NB * 1e-6 + 1e-6);
        double local = 0.0;
        for (int i = t; i < NB; i += 512) {
            const float rs = __hip_atomic_load(&rowsum[i], __ATOMIC_RELAXED,
                                               __HIP_MEMORY_SCOPE_AGENT);
            const float cs = __hip_atomic_load(&colsum[i], __ATOMIC_RELAXED,
                                               __HIP_MEMORY_SCOPE_AGENT);
            local += (double)sdiag[i] * (2.0 / 0.07)
                   - (double)logf(rs + extra)
                   - (double)logf(cs + extra);
        }
        #pragma unroll
        for (int off = 1; off < 64; off <<= 1)
            local += __shfl_xor(local, off, 64);
        if ((t & 63) == 0) dred[t >> 6] = local;
        __syncthreads();
        if (t == 0) {
            double tot = 0.0;
            #pragma unroll
            for (int w = 0; w < 8; ++w) tot += dred[w];
            out[0] = (float)(tot * (-1.0 / (2.0 * NB)));
        }
    }
}

// ---------------------------------------------------------------------------
extern "C" void kernel_launch(void* const* d_in, const int* in_sizes, int n_in,
                              void* d_out, int out_size, void* d_ws, size_t ws_size,
                              hipStream_t stream)
{
    const float* x = (const float*)d_in[0];
    const float* y = (const float*)d_in[1];
    float* out = (float*)d_out;

    char* ws = (char*)d_ws;
    unsigned char* xq = (unsigned char*)ws;                                 // 2 MB fp4 swizzled
    unsigned char* yq = (unsigned char*)(ws + (size_t)2 * 1024 * 1024);     // 2 MB fp4 swizzled
    float* rowsum = (float*)(ws + (size_t)8 * 1024 * 1024);                 // 16 KB
    float* colsum = rowsum + NB;                                            // 16 KB
    float* sdiag  = colsum + NB;                                            // 16 KB
    unsigned* donecnt = (unsigned*)(sdiag + NB);                            // 4 B

    normalize_rows<<<NB / 4, 256, 0, stream>>>(x, y, xq, yq, sdiag, rowsum);

    dim3 grid(16, 16);
    gemm_exp_sums<<<grid, 512, 0, stream>>>(xq, yq, rowsum, colsum,
                                            sdiag, donecnt, out);
}